// Round 1
// baseline (1529.845 us; speedup 1.0000x reference)
//
#include <hip/hip_runtime.h>
#include <cstdint>
#include <cstddef>

typedef _Float16 h2 __attribute__((ext_vector_type(2)));

#define S_LEN 2048
#define HDIM  256
#define BATCH 64

__device__ __forceinline__ float dot2f(h2 a, h2 b, float c) {
#if __has_builtin(__builtin_amdgcn_fdot2)
    return __builtin_amdgcn_fdot2(a, b, c, false);
#else
    return c + (float)a[0] * (float)b[0] + (float)a[1] * (float)b[1];
#endif
}

__device__ __forceinline__ float tanh_fast(float x) {
    // tanh(x) = 1 - 2/(exp(2x)+1); exact limits at +/-inf, ~1e-6 rel err
    return 1.0f - 2.0f / (__expf(2.0f * x) + 1.0f);
}

// ---------------------------------------------------------------------------
// Kernel A: xp[m, h] = sum_i x[m, i] * Wxh[h, i] + bxh[h]
// m = b*S + s in [0, 131072), h in [0, 256). Written into out[0 : B*S*H].
// Tiles: BM=64, BN=64, BK=32; 256 threads; 4x4 micro-tile per thread.
// ---------------------------------------------------------------------------
__global__ void __launch_bounds__(256) xp_gemm(
    const float* __restrict__ x, const float* __restrict__ Wxh,
    const float* __restrict__ bxh, float* __restrict__ out) {
    __shared__ float As[32][68];  // [k][m], stride 68 floats = 272 B (16B-aligned rows)
    __shared__ float Bs[32][68];  // [k][n]

    const int tid = threadIdx.x;
    const int tx = tid & 15;        // n-direction
    const int ty = tid >> 4;        // m-direction
    const size_t m0 = (size_t)blockIdx.x * 64;
    const int n0 = blockIdx.y * 64;

    // loader mapping: each thread loads two float4s per operand
    const int r = tid >> 3;         // 0..31
    const int c = (tid & 7) * 4;    // 0,4,...,28

    float bj[4];
#pragma unroll
    for (int j = 0; j < 4; j++) bj[j] = bxh[n0 + tx * 4 + j];

    float acc[4][4] = {};

    for (int k0 = 0; k0 < 256; k0 += 32) {
        float4 a0 = *(const float4*)&x[(m0 + r) * 256 + k0 + c];
        float4 a1 = *(const float4*)&x[(m0 + r + 32) * 256 + k0 + c];
        float4 b0 = *(const float4*)&Wxh[(size_t)(n0 + r) * 256 + k0 + c];
        float4 b1 = *(const float4*)&Wxh[(size_t)(n0 + r + 32) * 256 + k0 + c];

        __syncthreads();  // previous tile's compute done before overwrite
        As[c + 0][r] = a0.x; As[c + 1][r] = a0.y; As[c + 2][r] = a0.z; As[c + 3][r] = a0.w;
        As[c + 0][r + 32] = a1.x; As[c + 1][r + 32] = a1.y; As[c + 2][r + 32] = a1.z; As[c + 3][r + 32] = a1.w;
        Bs[c + 0][r] = b0.x; Bs[c + 1][r] = b0.y; Bs[c + 2][r] = b0.z; Bs[c + 3][r] = b0.w;
        Bs[c + 0][r + 32] = b1.x; Bs[c + 1][r + 32] = b1.y; Bs[c + 2][r + 32] = b1.z; Bs[c + 3][r + 32] = b1.w;
        __syncthreads();

#pragma unroll
        for (int kk = 0; kk < 32; kk++) {
            float4 av = *(const float4*)&As[kk][ty * 4];
            float4 bv = *(const float4*)&Bs[kk][tx * 4];
            float aa[4] = {av.x, av.y, av.z, av.w};
            float bb[4] = {bv.x, bv.y, bv.z, bv.w};
#pragma unroll
            for (int i = 0; i < 4; i++)
#pragma unroll
                for (int j = 0; j < 4; j++)
                    acc[i][j] = fmaf(aa[i], bb[j], acc[i][j]);
        }
    }

#pragma unroll
    for (int i = 0; i < 4; i++) {
        float4 o;
        o.x = acc[i][0] + bj[0];
        o.y = acc[i][1] + bj[1];
        o.z = acc[i][2] + bj[2];
        o.w = acc[i][3] + bj[3];
        *(float4*)&out[(m0 + ty * 4 + i) * 256 + n0 + tx * 4] = o;
    }
}

// ---------------------------------------------------------------------------
// Kernel B: sequential recurrence. One workgroup per batch element.
// 512 threads: thread (h = t>>1, half = t&1) owns W_hh[h][half*128 .. +128)
// as 64 packed f16 pairs in VGPRs. h vector carried in f16, double-buffered
// in LDS. In-place: reads xp from out, overwrites with h. Also writes h_last.
// ---------------------------------------------------------------------------
__global__ void __launch_bounds__(512) rnn_recur(
    const float* __restrict__ Whh, const float* __restrict__ bhh,
    float* __restrict__ out) {
    const int b = blockIdx.x;
    const int t = threadIdx.x;
    const int h = t >> 1;
    const int half = t & 1;

    // load + convert W row-slice into registers (one-time)
    h2 w[64];
    const float* wrow = Whh + (size_t)h * HDIM + half * 128;
#pragma unroll
    for (int j = 0; j < 32; j++) {
        float4 wv = *(const float4*)&wrow[4 * j];
        w[2 * j]     = h2{(_Float16)wv.x, (_Float16)wv.y};
        w[2 * j + 1] = h2{(_Float16)wv.z, (_Float16)wv.w};
    }
    const float bias = bhh[h];

    __shared__ __align__(16) _Float16 hbuf[2][HDIM];
    for (int i = t; i < HDIM; i += 512) hbuf[0][i] = (_Float16)0.f;
    __syncthreads();

    float* xprow = out + (size_t)b * S_LEN * HDIM;
    float* hlast = out + (size_t)BATCH * S_LEN * HDIM;

    int p = 0;
    float val = 0.f;
    for (int s = 0; s < S_LEN; s++) {
        // xp value needed at end of step; issue load early
        float xpv = xprow[(size_t)s * HDIM + h];

        const float4* hp4 = (const float4*)&hbuf[p][half * 128];
        float a0 = 0.f, a1 = 0.f, a2 = 0.f, a3 = 0.f;
#pragma unroll
        for (int j = 0; j < 16; j++) {
            float4 vv = hp4[j];
            a0 = dot2f(w[4 * j + 0], __builtin_bit_cast(h2, vv.x), a0);
            a1 = dot2f(w[4 * j + 1], __builtin_bit_cast(h2, vv.y), a1);
            a2 = dot2f(w[4 * j + 2], __builtin_bit_cast(h2, vv.z), a2);
            a3 = dot2f(w[4 * j + 3], __builtin_bit_cast(h2, vv.w), a3);
        }
        float part = (a0 + a1) + (a2 + a3);
        part += __shfl_xor(part, 1);  // pair (h,0)+(h,1): same wave, lockstep

        val = tanh_fast(part + bias + xpv);

        // half==1 lane writes h_seq output (overwrites xp slot, already read
        // this iteration by both lanes of the pair -- wave-lockstep safe);
        // half==0 lane posts f16 h into the other LDS buffer.
        if (half) {
            xprow[(size_t)s * HDIM + h] = val;
        } else {
            hbuf[p ^ 1][h] = (_Float16)val;
        }
        p ^= 1;
        __syncthreads();
    }
    if (!half) hlast[b * HDIM + h] = val;
}

extern "C" void kernel_launch(void* const* d_in, const int* in_sizes, int n_in,
                              void* d_out, int out_size, void* d_ws, size_t ws_size,
                              hipStream_t stream) {
    const float* x   = (const float*)d_in[0];
    const float* Wxh = (const float*)d_in[1];
    const float* bxh = (const float*)d_in[2];
    const float* Whh = (const float*)d_in[3];
    const float* bhh = (const float*)d_in[4];
    float* out = (float*)d_out;

    dim3 gridA(131072 / 64, 256 / 64);  // (2048, 4)
    xp_gemm<<<gridA, 256, 0, stream>>>(x, Wxh, bxh, out);
    rnn_recur<<<BATCH, 512, 0, stream>>>(Whh, bhh, out);
}

// Round 2
// 1450.290 us; speedup vs baseline: 1.0549x; 1.0549x over previous
//
#include <hip/hip_runtime.h>
#include <cstdint>
#include <cstddef>

typedef _Float16 h2 __attribute__((ext_vector_type(2)));

#define S_LEN 2048
#define HDIM  256
#define BATCH 64
#define HPAD  144   // per-half stride in f16 units (128 data + 16 pad = 288 B)

__device__ __forceinline__ float dot2f(h2 a, h2 b, float c) {
#if __has_builtin(__builtin_amdgcn_fdot2)
    return __builtin_amdgcn_fdot2(a, b, c, false);
#else
    return c + (float)a[0] * (float)b[0] + (float)a[1] * (float)b[1];
#endif
}

__device__ __forceinline__ float tanh_fast(float x) {
    // tanh(x) = 1 - 2/(exp(2x)+1); exact limits at +/-inf, ~1e-6 rel err
    return 1.0f - 2.0f / (__expf(2.0f * x) + 1.0f);
}

// ---------------------------------------------------------------------------
// Kernel A: xp[m, h] = sum_i x[m, i] * Wxh[h, i] + bxh[h]   (unchanged)
// ---------------------------------------------------------------------------
__global__ void __launch_bounds__(256) xp_gemm(
    const float* __restrict__ x, const float* __restrict__ Wxh,
    const float* __restrict__ bxh, float* __restrict__ out) {
    __shared__ float As[32][68];
    __shared__ float Bs[32][68];

    const int tid = threadIdx.x;
    const int tx = tid & 15;
    const int ty = tid >> 4;
    const size_t m0 = (size_t)blockIdx.x * 64;
    const int n0 = blockIdx.y * 64;

    const int r = tid >> 3;
    const int c = (tid & 7) * 4;

    float bj[4];
#pragma unroll
    for (int j = 0; j < 4; j++) bj[j] = bxh[n0 + tx * 4 + j];

    float acc[4][4] = {};

    for (int k0 = 0; k0 < 256; k0 += 32) {
        float4 a0 = *(const float4*)&x[(m0 + r) * 256 + k0 + c];
        float4 a1 = *(const float4*)&x[(m0 + r + 32) * 256 + k0 + c];
        float4 b0 = *(const float4*)&Wxh[(size_t)(n0 + r) * 256 + k0 + c];
        float4 b1 = *(const float4*)&Wxh[(size_t)(n0 + r + 32) * 256 + k0 + c];

        __syncthreads();
        As[c + 0][r] = a0.x; As[c + 1][r] = a0.y; As[c + 2][r] = a0.z; As[c + 3][r] = a0.w;
        As[c + 0][r + 32] = a1.x; As[c + 1][r + 32] = a1.y; As[c + 2][r + 32] = a1.z; As[c + 3][r + 32] = a1.w;
        Bs[c + 0][r] = b0.x; Bs[c + 1][r] = b0.y; Bs[c + 2][r] = b0.z; Bs[c + 3][r] = b0.w;
        Bs[c + 0][r + 32] = b1.x; Bs[c + 1][r + 32] = b1.y; Bs[c + 2][r + 32] = b1.z; Bs[c + 3][r + 32] = b1.w;
        __syncthreads();

#pragma unroll
        for (int kk = 0; kk < 32; kk++) {
            float4 av = *(const float4*)&As[kk][ty * 4];
            float4 bv = *(const float4*)&Bs[kk][tx * 4];
            float aa[4] = {av.x, av.y, av.z, av.w};
            float bb[4] = {bv.x, bv.y, bv.z, bv.w};
#pragma unroll
            for (int i = 0; i < 4; i++)
#pragma unroll
                for (int j = 0; j < 4; j++)
                    acc[i][j] = fmaf(aa[i], bb[j], acc[i][j]);
        }
    }

#pragma unroll
    for (int i = 0; i < 4; i++) {
        float4 o;
        o.x = acc[i][0] + bj[0];
        o.y = acc[i][1] + bj[1];
        o.z = acc[i][2] + bj[2];
        o.w = acc[i][3] + bj[3];
        *(float4*)&out[(m0 + ty * 4 + i) * 256 + n0 + tx * 4] = o;
    }
}

// ---------------------------------------------------------------------------
// Kernel B: recurrence. Changes vs R1:
//   - padded per-half LDS layout (stride 144 f16 = 288 B): the two broadcast
//     address groups within a wave now hit disjoint banks (0-3 vs 8-11)
//   - xp prefetched one full step ahead (register-carried)
// ---------------------------------------------------------------------------
__global__ void __launch_bounds__(512) rnn_recur(
    const float* __restrict__ Whh, const float* __restrict__ bhh,
    float* __restrict__ out) {
    const int b = blockIdx.x;
    const int t = threadIdx.x;
    const int h = t >> 1;
    const int half = t & 1;

    // one-time: W_hh half-row into registers as packed f16 pairs
    h2 w[64];
    const float* wrow = Whh + (size_t)h * HDIM + half * 128;
#pragma unroll
    for (int j = 0; j < 32; j++) {
        float4 wv = *(const float4*)&wrow[4 * j];
        w[2 * j]     = h2{(_Float16)wv.x, (_Float16)wv.y};
        w[2 * j + 1] = h2{(_Float16)wv.z, (_Float16)wv.w};
    }
    const float bias = bhh[h];

    __shared__ __align__(16) _Float16 hbuf[2][2 * HPAD];
    for (int i = t; i < 2 * 2 * HPAD; i += 512) ((_Float16*)hbuf)[i] = (_Float16)0.f;
    __syncthreads();

    float* xprow = out + (size_t)b * S_LEN * HDIM;
    float* hlast = out + (size_t)BATCH * S_LEN * HDIM;

    const int widx = h + ((h >> 7) << 4);  // skip the 16-f16 pad for upper half

    int p = 0;
    float val = 0.f;
    float xpv = xprow[h];  // xp[s=0]
    for (int s = 0; s < S_LEN; s++) {
        // prefetch next step's xp (row s+1 is only overwritten at step s+1,
        // which is after the barrier that ends this step -> race-free)
        const int sn = (s + 1 < S_LEN) ? s + 1 : s;
        float xpn = xprow[(size_t)sn * HDIM + h];

        const float4* hp4 = (const float4*)&hbuf[p][half * HPAD];
        float a0 = 0.f, a1 = 0.f, a2 = 0.f, a3 = 0.f;
#pragma unroll
        for (int j = 0; j < 16; j++) {
            float4 vv = hp4[j];
            a0 = dot2f(w[4 * j + 0], __builtin_bit_cast(h2, vv.x), a0);
            a1 = dot2f(w[4 * j + 1], __builtin_bit_cast(h2, vv.y), a1);
            a2 = dot2f(w[4 * j + 2], __builtin_bit_cast(h2, vv.z), a2);
            a3 = dot2f(w[4 * j + 3], __builtin_bit_cast(h2, vv.w), a3);
        }
        float part = (a0 + a1) + (a2 + a3);
        part += __shfl_xor(part, 1);  // pair (h,0)+(h,1): same wave, lockstep

        val = tanh_fast(part + bias + xpv);

        if (half) {
            xprow[(size_t)s * HDIM + h] = val;   // h_seq output (f32)
        } else {
            hbuf[p ^ 1][widx] = (_Float16)val;   // post h for next step
        }
        xpv = xpn;
        p ^= 1;
        __syncthreads();
    }
    if (!half) hlast[b * HDIM + h] = val;
}

extern "C" void kernel_launch(void* const* d_in, const int* in_sizes, int n_in,
                              void* d_out, int out_size, void* d_ws, size_t ws_size,
                              hipStream_t stream) {
    const float* x   = (const float*)d_in[0];
    const float* Wxh = (const float*)d_in[1];
    const float* bxh = (const float*)d_in[2];
    const float* Whh = (const float*)d_in[3];
    const float* bhh = (const float*)d_in[4];
    float* out = (float*)d_out;

    dim3 gridA(131072 / 64, 256 / 64);  // (2048, 4)
    xp_gemm<<<gridA, 256, 0, stream>>>(x, Wxh, bxh, out);
    rnn_recur<<<BATCH, 512, 0, stream>>>(Whh, bhh, out);
}